// Round 7
// baseline (1142.525 us; speedup 1.0000x reference)
//
#include <hip/hip_runtime.h>

// Problem constants: B=1, C=2, H=W=64, m=8192, mk=64, K1=K2=36, K3=2, Kc=2592, iters=6 (5 steps).
#define KC 2592
#define KCP 2624           // padded NtT row stride (zeros in tail)
#define HW 4096

// workspace layout (float offsets), total 2822144 floats = 11.29 MB
#define OFF_L    0u
#define OFF_S    8192u
#define OFF_MT   16384u    // Mt[64][8192]
#define OFF_NTT  540672u   // NtT[64][2624], layout d=(kk*36+ii)*36+jj, cols 2592..2623 zero
#define OFF_BIG  708608u   // Rpart[256][8192] / T1t[256][8192] / (Up[6][64][2592] + ACLp + Q)
#define OFF_GRAM 2805760u  // raw gram 64x64 (shared by Cm and Cn phases)
#define OFF_CMI  2809856u
#define OFF_CNI  2813952u
#define OFF_ST   2818048u  // inv phase-chain state (64x64) for the Cm split phases
// aliased into Big (lifetimes: T1t dead after k_mn; these live k_acl..k_nn2):
#define OFF_UP   708608u              // Up[6][64][2592] = 995328
#define OFF_ACLP (708608u + 1048576u) // ACLp[2][8192] c-partials
#define OFF_Q    (708608u + 1114112u) // Q[64][64]

__global__ __launch_bounds__(256) void k_init(const float* __restrict__ inp, const float* __restrict__ s0,
                                              float* __restrict__ L, float* __restrict__ S,
                                              float* __restrict__ Mt, float* __restrict__ NtT){
  int t = blockIdx.x * 256 + threadIdx.x;
  if (t < 8192){ L[t] = inp[t]; S[t] = s0[t]; }
  if (t < 524288){ int r = t >> 13; int p = t & 8191; Mt[t] = (p == r) ? 1.0f : 0.0f; }
  if (t < 167936){ int r = t / KCP; int d = t - r * KCP;
                   int dr = (r % 36) * 36 + r / 36;   // N0: d=(0*36+ii)*36+jj with col=jj*36+ii=r
                   NtT[t] = (d == dr) ? 1.0f : 0.0f; }
}

// ---- in-register Jordan-exchange inverse of (2g*gram + a*I), SPD, no pivoting.
// Cm inv: proven R8 split-phase unrolled version hosted in conv_R/conv_T1 sentinels.
// Cn inv (R15): LOOPED small-code version (static register indices, runtime-K readlane,
// uniform selects) — ~3.6KB loop body avoids the ~100KB icache stream of the unrolled form,
// so it can ride in the small k_acl kernel. Arithmetic identical per element.
__device__ __forceinline__ float readlane_f(float x, int lane){
  return __uint_as_float(__builtin_amdgcn_readlane(__float_as_uint(x), lane));
}
template<int K>
__device__ __forceinline__ void gj_step(float (&b)[64], int lane){
  float bk = b[K];
  float akk = readlane_f(bk, K);
  float p = 1.0f / akk;
  bool isk = (lane == K);
  float t = isk ? 1.0f : bk;
  float pt = p * t;
  #pragma unroll
  for (int g = 0; g < 4; g++){
    float f[16];
    #pragma unroll
    for (int u = 0; u < 16; u++){
      int i = g * 16 + u;
      if (i == K) continue;
      f[u] = readlane_f(b[i], K);
    }
    #pragma unroll
    for (int u = 0; u < 16; u++){
      int i = g * 16 + u;
      if (i == K) continue;
      float base = isk ? 0.0f : b[i];
      b[i] = fmaf(-f[u], pt, base);
    }
  }
  b[K] = t * p;
}
template<int K0, int K1> struct GJR {
  static __device__ __forceinline__ void run(float (&b)[64], int lane){
    gj_step<K0>(b, lane);
    GJR<K0 + 1, K1>::run(b, lane);
  }
};
template<int KE> struct GJR<KE, KE> {
  static __device__ __forceinline__ void run(float (&b)[64], int lane){}
};
template<int PH>
__device__ void inv64_phaseA(const float* __restrict__ src, const float* __restrict__ pg,
                             const float* __restrict__ pa, float* __restrict__ state, int lane){
  float scale = 2.0f * pg[0];
  float ad = pa[0];
  float b[64];
  #pragma unroll
  for (int i = 0; i < 64; i++)
    b[i] = scale * src[i * 64 + lane] + ((i == lane) ? ad : 0.0f);
  GJR<0, PH>::run(b, lane);
  #pragma unroll
  for (int i = 0; i < 64; i++) state[i * 64 + lane] = b[i];
}
template<int PH>
__device__ void inv64_phaseB(const float* __restrict__ state, float* __restrict__ dst, int lane){
  float b[64];
  #pragma unroll
  for (int i = 0; i < 64; i++) b[i] = state[i * 64 + lane];
  GJR<PH, 64>::run(b, lane);
  #pragma unroll
  for (int i = 0; i < 64; i++) dst[i * 64 + lane] = b[i];
}
// looped inverse: same arithmetic as GJR<0,64>, K dynamic. b[i]/f[i] statically indexed
// (unrolled i-loops); b[K] extracted via uniform select-chain; lane index K is SGPR-legal.
__device__ void inv64_loop(const float* __restrict__ src, const float* __restrict__ pg,
                           const float* __restrict__ pa, float* __restrict__ dst, int lane){
  float scale = 2.0f * pg[0];
  float ad = pa[0];
  float b[64];
  #pragma unroll
  for (int i = 0; i < 64; i++)
    b[i] = scale * src[i * 64 + lane] + ((i == lane) ? ad : 0.0f);
  for (int K = 0; K < 64; K++){
    float bK = b[0];
    #pragma unroll
    for (int i = 1; i < 64; i++) bK = (i == K) ? b[i] : bK;   // uniform select-chain
    float akk = readlane_f(bK, K);
    float p = 1.0f / akk;
    bool isk = (lane == K);
    float t = isk ? 1.0f : bK;
    float pt = p * t;
    float f[64];
    #pragma unroll
    for (int i = 0; i < 64; i++) f[i] = readlane_f(b[i], K);
    float rowk = t * p;
    #pragma unroll
    for (int i = 0; i < 64; i++){
      float base = isk ? 0.0f : b[i];
      float upd = fmaf(-f[i], pt, base);
      b[i] = (i == K) ? rowk : upd;
    }
  }
  #pragma unroll
  for (int i = 0; i < 64; i++) dst[i * 64 + lane] = b[i];
}

// ---- conv_R (+ fused inv(Cm) PHASE A as sentinel z==4): R12-proven single-wave blocks.
__global__ __launch_bounds__(64) void k_conv_R(const float* __restrict__ Mtg,
                                               const float* __restrict__ NtT,
                                               float* __restrict__ Rpart,
                                               const float* __restrict__ Gr,
                                               const float* __restrict__ pg,
                                               const float* __restrict__ pa,
                                               float* __restrict__ state){
  __shared__ float img[2][16][68];
  __shared__ float4 filt4[162];
  if (blockIdx.z == 4){
    if (blockIdx.x == 0 && blockIdx.y == 0)
      inv64_phaseA<32>(Gr, pg, pa, state, threadIdx.x);
    return;
  }
  int r = blockIdx.x, oct = blockIdx.y, z = blockIdx.z, tid = threadIdx.x;
  int rowbase = oct * 8 + z * 9;
  const float4* gi4 = (const float4*)(Mtg + (size_t)r * 8192);
  for (int t = tid; t < 512; t += 64){
    int fw = t & 15, rr = t >> 4;
    int c = rr >> 4, q = rr & 15;
    int gr = (rowbase + q) & 63;
    float4 v4 = gi4[(c * 64 + gr) * 16 + fw];
    float* d = &img[c][q][fw * 4];
    d[0] = v4.x; d[1] = v4.y; d[2] = v4.z; d[3] = v4.w;
  }
  int iilo = z * 9;
  const float* gf = NtT + (size_t)r * KCP;
  for (int t = tid; t < 162; t += 64){
    int kk = t / 81; int rem4 = t - kk * 81;
    filt4[t] = *(const float4*)(gf + kk * 1296 + iilo * 36 + rem4 * 4);
  }
  __syncthreads();
  int c0 = tid >> 5, hl = (tid >> 2) & 7, w0 = (tid & 3) * 16;
  float acc[16];
  #pragma unroll
  for (int u = 0; u < 16; u++) acc[u] = 0.0f;
  #pragma unroll 1
  for (int kk = 0; kk < 2; kk++){
    int cimg = (c0 + kk) & 1;
    #pragma unroll 1
    for (int iix = 0; iix < 9; iix++){
      const float* ib = img[cimg][hl + iix];
      float v[32];
      #pragma unroll
      for (int t = 0; t < 8; t++){
        float4 t4 = *(const float4*)&ib[(w0 + 4 * t) & 63];
        v[4*t] = t4.x; v[4*t+1] = t4.y; v[4*t+2] = t4.z; v[4*t+3] = t4.w;
      }
      const float4* fb = &filt4[kk * 81 + iix * 9];
      #pragma unroll
      for (int g = 0; g < 9; g++){
        float4 ff = fb[g];
        #pragma unroll
        for (int u = 0; u < 16; u++) acc[u] = fmaf(ff.x, v[(4*g + 0 + u) & 31], acc[u]);
        #pragma unroll
        for (int u = 0; u < 16; u++) acc[u] = fmaf(ff.y, v[(4*g + 1 + u) & 31], acc[u]);
        #pragma unroll
        for (int u = 0; u < 16; u++) acc[u] = fmaf(ff.z, v[(4*g + 2 + u) & 31], acc[u]);
        #pragma unroll
        for (int u = 0; u < 16; u++) acc[u] = fmaf(ff.w, v[(4*g + 3 + u) & 31], acc[u]);
        if (g < 5){
          float4 nv = *(const float4*)&ib[(w0 + 32 + 4*g) & 63];
          int s = (4*g) & 31;
          v[s] = nv.x; v[s+1] = nv.y; v[s+2] = nv.z; v[s+3] = nv.w;
        }
      }
    }
  }
  int h = oct * 8 + hl;
  size_t ob = ((size_t)r + 64 * z) * 8192 + (size_t)(c0 * HW + h * 64 + w0);
  *(float4*)&Rpart[ob]      = make_float4(acc[0], acc[1], acc[2], acc[3]);
  *(float4*)&Rpart[ob + 4]  = make_float4(acc[4], acc[5], acc[6], acc[7]);
  *(float4*)&Rpart[ob + 8]  = make_float4(acc[8], acc[9], acc[10], acc[11]);
  *(float4*)&Rpart[ob + 12] = make_float4(acc[12], acc[13], acc[14], acc[15]);
}

// ---- conv_T1 (+ fused inv(Cm) PHASE B as sentinel z==4): R12-proven.
__global__ __launch_bounds__(64) void k_conv_T1(const float* __restrict__ Lg,
                                                const float* __restrict__ NtT,
                                                float* __restrict__ T1t,
                                                const float* __restrict__ state,
                                                float* __restrict__ CmI){
  __shared__ float img[2][16][68];
  __shared__ float4 filt4[162];
  if (blockIdx.z == 4){
    if (blockIdx.x == 0 && blockIdx.y == 0)
      inv64_phaseB<32>(state, CmI, threadIdx.x);
    return;
  }
  int r = blockIdx.x, oct = blockIdx.y, z = blockIdx.z, tid = threadIdx.x;
  int rowbase = (oct * 8 - z * 9 - 8 + 128) & 63;
  const float4* gi4 = (const float4*)Lg;
  for (int t = tid; t < 512; t += 64){
    int fw = t & 15, rr = t >> 4;
    int c = rr >> 4, q = rr & 15;
    int gr = (rowbase + q) & 63;
    float4 v4 = gi4[(c * 64 + gr) * 16 + fw];
    float* d = &img[c][q][fw * 4];
    d[0] = v4.x; d[1] = v4.y; d[2] = v4.z; d[3] = v4.w;
  }
  int iilo = z * 9;
  const float* gf = NtT + (size_t)r * KCP;
  for (int t = tid; t < 162; t += 64){
    int kk = t / 81; int rem4 = t - kk * 81;
    filt4[t] = *(const float4*)(gf + kk * 1296 + iilo * 36 + rem4 * 4);
  }
  __syncthreads();
  int c0 = tid >> 5, hl = (tid >> 2) & 7, w0 = (tid & 3) * 16;
  float acc[16];
  #pragma unroll
  for (int u = 0; u < 16; u++) acc[u] = 0.0f;
  #pragma unroll 1
  for (int kk = 0; kk < 2; kk++){
    int cimg = (c0 - kk + 2) & 1;
    #pragma unroll 1
    for (int iix = 0; iix < 9; iix++){
      const float* ib = img[cimg][hl - iix + 8];
      float v[32];
      {
        float4 tm = *(const float4*)&ib[(w0 - 4 + 64) & 63];
        v[28] = tm.x; v[29] = tm.y; v[30] = tm.z; v[31] = tm.w;
      }
      #pragma unroll
      for (int t = 0; t < 4; t++){
        float4 t4 = *(const float4*)&ib[(w0 + 4 * t) & 63];
        v[4*t] = t4.x; v[4*t+1] = t4.y; v[4*t+2] = t4.z; v[4*t+3] = t4.w;
      }
      const float4* fb = &filt4[kk * 81 + iix * 9];
      #pragma unroll
      for (int g = 0; g < 9; g++){
        float4 ff = fb[g];
        #pragma unroll
        for (int u = 0; u < 16; u++) acc[u] = fmaf(ff.x, v[(u - (4*g + 0)) & 31], acc[u]);
        #pragma unroll
        for (int u = 0; u < 16; u++) acc[u] = fmaf(ff.y, v[(u - (4*g + 1)) & 31], acc[u]);
        #pragma unroll
        for (int u = 0; u < 16; u++) acc[u] = fmaf(ff.z, v[(u - (4*g + 2)) & 31], acc[u]);
        #pragma unroll
        for (int u = 0; u < 16; u++) acc[u] = fmaf(ff.w, v[(u - (4*g + 3)) & 31], acc[u]);
        if (g < 8){
          float4 nv = *(const float4*)&ib[(w0 - 8 - 4*g + 128) & 63];
          int s = (-8 - 4*g) & 31;
          v[s] = nv.x; v[s+1] = nv.y; v[s+2] = nv.z; v[s+3] = nv.w;
        }
      }
    }
  }
  int h = oct * 8 + hl;
  size_t ob = ((size_t)r + 64 * z) * 8192 + (size_t)(c0 * HW + h * 64 + w0);
  *(float4*)&T1t[ob]      = make_float4(acc[0], acc[1], acc[2], acc[3]);
  *(float4*)&T1t[ob + 4]  = make_float4(acc[4], acc[5], acc[6], acc[7]);
  *(float4*)&T1t[ob + 8]  = make_float4(acc[8], acc[9], acc[10], acc[11]);
  *(float4*)&T1t[ob + 12] = make_float4(acc[12], acc[13], acc[14], acc[15]);
}

// L[p] = clip((inp - S + g*R)/(g+1)); S = (inp - L)/(b+1)
__global__ __launch_bounds__(256) void k_reduce_LS(const float* __restrict__ Rpart,
                                                   const float* __restrict__ inp,
                                                   const float* __restrict__ pg, const float* __restrict__ pb,
                                                   float* __restrict__ S, float* __restrict__ Ldst){
  __shared__ float red[8][32];
  int tid = threadIdx.x;
  int pi = tid & 31, sg = tid >> 5;
  int p = blockIdx.x * 32 + pi;
  float acc = 0.0f;
  #pragma unroll 4
  for (int s = sg * 32; s < sg * 32 + 32; s++) acc += Rpart[(size_t)s * 8192 + p];
  red[sg][pi] = acc;
  __syncthreads();
  if (tid < 32){
    float a = 0.0f;
    #pragma unroll
    for (int q = 0; q < 8; q++) a += red[q][pi];
    float R = a * (1.0f / 2592.0f);
    float g = pg[0], b = pb[0];
    float Ln = (inp[p] - S[p] + g * R) / (g + 1.0f);
    Ln = fminf(fmaxf(Ln, 0.0f), 1.0f);
    S[p] = (inp[p] - Ln) / (b + 1.0f);
    Ldst[p] = Ln;
  }
}

// raw gram
__global__ __launch_bounds__(64) void k_gram(const float* __restrict__ rows, int stride, int len4,
                                             float* __restrict__ out){
  int e = blockIdx.x; int r1 = e >> 6, r2 = e & 63;
  if (r2 < r1) return;
  int lane = threadIdx.x;
  const float4* a = (const float4*)(rows + (size_t)r1 * stride);
  const float4* b = (const float4*)(rows + (size_t)r2 * stride);
  float acc = 0.0f;
  for (int p = lane; p < len4; p += 64){
    float4 x = a[p], y = b[p];
    acc = fmaf(x.x, y.x, acc); acc = fmaf(x.y, y.y, acc);
    acc = fmaf(x.z, y.z, acc); acc = fmaf(x.w, y.w, acc);
  }
  for (int off = 32; off; off >>= 1) acc += __shfl_down(acc, off, 64);
  if (lane == 0){ out[r1 * 64 + r2] = acc; out[r2 * 64 + r1] = acc; }
}

// Mt_new[s][p] = 2g * sum_r T1c[r][p] * CmInv[r][s]
__global__ __launch_bounds__(256) void k_mn(const float* __restrict__ T1t, const float* __restrict__ CmInv,
                                            const float* __restrict__ pg, float* __restrict__ Mt){
  __shared__ float4 ci4[1024];
  int tid = threadIdx.x;
  const float4* g4 = (const float4*)CmInv;
  for (int t = tid; t < 1024; t += 256) ci4[t] = g4[t];
  __syncthreads();
  int p = blockIdx.x * 256 + tid;
  int sbase = blockIdx.y * 32;
  float g2 = 2.0f * pg[0];
  float acc[32];
  #pragma unroll
  for (int s = 0; s < 32; s++) acc[s] = 0.0f;
  for (int r = 0; r < 64; r++){
    float v = T1t[(size_t)r * 8192 + p] + T1t[(size_t)(r + 64) * 8192 + p]
            + T1t[(size_t)(r + 128) * 8192 + p] + T1t[(size_t)(r + 192) * 8192 + p];
    #pragma unroll
    for (int k = 0; k < 8; k++){
      float4 c = ci4[r * 16 + (sbase >> 2) + k];
      acc[4*k+0] = fmaf(v, c.x, acc[4*k+0]);
      acc[4*k+1] = fmaf(v, c.y, acc[4*k+1]);
      acc[4*k+2] = fmaf(v, c.z, acc[4*k+2]);
      acc[4*k+3] = fmaf(v, c.w, acc[4*k+3]);
    }
  }
  #pragma unroll
  for (int s = 0; s < 32; s++) Mt[(size_t)(sbase + s) * 8192 + p] = g2 * acc[s];
}

// ---- R15: k_acl — cyclic autocorrelation of L over Z2 x Z64 x Z64 (c-partials), plus
// sentinel block 256 = full looped inv(Cn) -> CnI.
// ACLp[cc][kt*4096 + it*64 + jt] = sum_{h,w} L[cc,h,w] * L[(cc+kt)%2,(h+it)%64,(w+jt)%64]
__global__ __launch_bounds__(256) void k_acl(const float* __restrict__ Lg,
                                             float* __restrict__ ACLp,
                                             const float* __restrict__ Gr,
                                             const float* __restrict__ pg,
                                             const float* __restrict__ pa,
                                             float* __restrict__ CnI){
  __shared__ float Ls[128 * 68];
  __shared__ float sred[16 * 68];
  if (blockIdx.x == 256){
    if (threadIdx.x < 64)
      inv64_loop(Gr, pg, pa, CnI, threadIdx.x);
    return;
  }
  int bx = blockIdx.x, tid = threadIdx.x;
  int kt = bx >> 7, it = (bx >> 1) & 63, cc = bx & 1;
  const float4* gl4 = (const float4*)Lg;
  for (int t = tid; t < 2048; t += 256){
    int row = t >> 4, c4 = t & 15;
    float4 v4 = gl4[row * 16 + c4];
    float* d = &Ls[row * 68 + c4 * 4];
    d[0] = v4.x; d[1] = v4.y; d[2] = v4.z; d[3] = v4.w;
  }
  __syncthreads();
  int j4 = tid & 15;                                  // jt0 = j4*4
  int hgw = ((tid >> 4) & 3) | ((tid >> 6) << 2);     // 0..15, unique per thread triple
  float acc[4] = {0.f, 0.f, 0.f, 0.f};
  int rb1 = cc * 64, rb2 = ((cc + kt) & 1) * 64;
  #pragma unroll 1
  for (int hl = 0; hl < 4; hl++){
    int h = hl * 16 + hgw;
    const float* r1 = &Ls[(rb1 + h) * 68];
    const float* r2 = &Ls[(rb2 + ((h + it) & 63)) * 68];
    float v[32];
    #pragma unroll
    for (int t = 0; t < 8; t++){
      float4 t4 = *(const float4*)&r2[((j4 + t) & 15) * 4];
      v[4*t] = t4.x; v[4*t+1] = t4.y; v[4*t+2] = t4.z; v[4*t+3] = t4.w;
    }
    float head[4] = {v[0], v[1], v[2], v[3]};
    #pragma unroll
    for (int g = 0; g < 16; g++){
      float4 ff = *(const float4*)&r1[g * 4];
      #pragma unroll
      for (int e = 0; e < 4; e++){
        float fv = (e == 0) ? ff.x : (e == 1) ? ff.y : (e == 2) ? ff.z : ff.w;
        #pragma unroll
        for (int u = 0; u < 4; u++){
          int x = 4 * g + e + u;                       // logical: r2[(jt0+x)&63]
          float val = (x < 64) ? v[x & 31] : head[x - 64];
          acc[u] = fmaf(fv, val, acc[u]);
        }
      }
      if (g < 8){
        float4 nv = *(const float4*)&r2[((j4 + 8 + g) & 15) * 4];
        int s = (4 * g) & 31;
        v[s] = nv.x; v[s+1] = nv.y; v[s+2] = nv.z; v[s+3] = nv.w;
      }
    }
  }
  #pragma unroll
  for (int u = 0; u < 4; u++) sred[hgw * 68 + j4 * 4 + u] = acc[u];
  __syncthreads();
  if (tid < 64){
    float s = 0.0f;
    #pragma unroll
    for (int q = 0; q < 16; q++) s += sred[q * 68 + tid];
    ACLp[cc * 8192 + kt * 4096 + it * 64 + tid] = s;
  }
}

// ---- R15: k_ucv — U[r][delta] = sum_sigma NtT_old[r][sigma] * ACL(delta - sigma).
// Grid (64, 7): y<6 covers 12 sigma-rows each (rho = y*12+l); partials Up[y].
// y==6,x==0 sentinel: Q[r][rr] = (2g)^2 sum_s CmI[r][s]*CnI[s][rr].
// Inner loop = conv_T1's proven downward ring with 12 accs; output col layout matches
// the old T2sum (kk_d*1296 + jj_d*36 + ii_d) so k_nn2 keeps the d-permutation.
__global__ __launch_bounds__(256) void k_ucv(const float* __restrict__ NtT,
                                             const float* __restrict__ ACLp,
                                             float* __restrict__ Up,
                                             const float* __restrict__ CmI,
                                             const float* __restrict__ CnI,
                                             const float* __restrict__ pg,
                                             float* __restrict__ Q){
  __shared__ float Acl[128 * 68];
  __shared__ float4 filt4[108];
  if (blockIdx.y == 6){
    if (blockIdx.x == 0 && threadIdx.x < 64){
      int rr = threadIdx.x;
      float cn[64];
      #pragma unroll
      for (int s = 0; s < 64; s++) cn[s] = CnI[s * 64 + rr];
      float g2 = 2.0f * pg[0];
      float g22 = g2 * g2;
      for (int r = 0; r < 64; r++){
        float q = 0.0f;
        #pragma unroll
        for (int s = 0; s < 64; s++) q = fmaf(CmI[r * 64 + s], cn[s], q);
        Q[r * 64 + rr] = g22 * q;
      }
    }
    return;
  }
  int r = blockIdx.x, y = blockIdx.y, tid = threadIdx.x;
  const float4* ap4 = (const float4*)ACLp;
  for (int t = tid; t < 2048; t += 256){
    int row = t >> 4, c4 = t & 15;
    float4 a0 = ap4[row * 16 + c4];
    float4 a1 = ap4[2048 + row * 16 + c4];
    float* d = &Acl[row * 68 + c4 * 4];
    d[0] = a0.x + a1.x; d[1] = a0.y + a1.y; d[2] = a0.z + a1.z; d[3] = a0.w + a1.w;
  }
  const float* gf = NtT + (size_t)r * KCP + y * 432;
  for (int t = tid; t < 108; t += 256) filt4[t] = *(const float4*)(gf + t * 4);
  __syncthreads();
  if (tid >= 216) return;
  int kk_s = y / 3;
  int kk_d = tid / 108, rest = tid % 108, ii_d = rest / 3, jj0 = (rest % 3) * 12;
  float acc[12];
  #pragma unroll
  for (int u = 0; u < 12; u++) acc[u] = 0.0f;
  #pragma unroll 1
  for (int l = 0; l < 12; l++){
    int ii_s = y * 12 + l - kk_s * 36;
    int kt = (kk_d - kk_s) & 1;
    int it = (ii_d - ii_s) & 63;
    const float* ib = &Acl[(kt * 64 + it) * 68];
    float v[32];
    {
      float4 tm = *(const float4*)&ib[(jj0 - 4 + 64) & 63];
      v[28] = tm.x; v[29] = tm.y; v[30] = tm.z; v[31] = tm.w;
    }
    #pragma unroll
    for (int t = 0; t < 4; t++){
      float4 t4 = *(const float4*)&ib[(jj0 + 4 * t) & 63];
      v[4*t] = t4.x; v[4*t+1] = t4.y; v[4*t+2] = t4.z; v[4*t+3] = t4.w;
    }
    const float4* fb = &filt4[l * 9];
    #pragma unroll
    for (int g = 0; g < 9; g++){
      float4 ff = fb[g];
      #pragma unroll
      for (int u = 0; u < 12; u++) acc[u] = fmaf(ff.x, v[(u - (4*g + 0)) & 31], acc[u]);
      #pragma unroll
      for (int u = 0; u < 12; u++) acc[u] = fmaf(ff.y, v[(u - (4*g + 1)) & 31], acc[u]);
      #pragma unroll
      for (int u = 0; u < 12; u++) acc[u] = fmaf(ff.z, v[(u - (4*g + 2)) & 31], acc[u]);
      #pragma unroll
      for (int u = 0; u < 12; u++) acc[u] = fmaf(ff.w, v[(u - (4*g + 3)) & 31], acc[u]);
      if (g < 8){
        float4 nv = *(const float4*)&ib[(jj0 - 8 - 4*g + 128) & 63];
        int s = (-8 - 4*g) & 31;
        v[s] = nv.x; v[s+1] = nv.y; v[s+2] = nv.z; v[s+3] = nv.w;
      }
    }
  }
  #pragma unroll
  for (int u = 0; u < 12; u++){
    int col = kk_d * 1296 + (jj0 + u) * 36 + ii_d;
    Up[(size_t)y * 165888 + (size_t)r * KC + col] = acc[u];
  }
}

// ---- R15: k_nn2 — NtT_new[rr][d(col)] = sum_r Q[r][rr] * (sum_{y<6} Up[y][r][col])
__global__ __launch_bounds__(256) void k_nn2(const float* __restrict__ Up, const float* __restrict__ Q,
                                             float* __restrict__ NtT){
  __shared__ float4 q4[1024];
  int tid = threadIdx.x;
  const float4* g4 = (const float4*)Q;
  for (int t = tid; t < 1024; t += 256) q4[t] = g4[t];
  __syncthreads();
  int col = blockIdx.x * 256 + tid;
  if (col >= KC) return;
  int rb = blockIdx.y * 16;
  float acc[16];
  #pragma unroll
  for (int rr = 0; rr < 16; rr++) acc[rr] = 0.0f;
  for (int r = 0; r < 64; r++){
    float tv = Up[(size_t)r * KC + col]
             + Up[(size_t)165888 + (size_t)r * KC + col]
             + Up[(size_t)331776 + (size_t)r * KC + col]
             + Up[(size_t)497664 + (size_t)r * KC + col]
             + Up[(size_t)663552 + (size_t)r * KC + col]
             + Up[(size_t)829440 + (size_t)r * KC + col];
    #pragma unroll
    for (int k = 0; k < 4; k++){
      float4 c = q4[r * 16 + (rb >> 2) + k];
      acc[4*k+0] = fmaf(tv, c.x, acc[4*k+0]);
      acc[4*k+1] = fmaf(tv, c.y, acc[4*k+1]);
      acc[4*k+2] = fmaf(tv, c.z, acc[4*k+2]);
      acc[4*k+3] = fmaf(tv, c.w, acc[4*k+3]);
    }
  }
  int kk = col / 1296, rest = col % 1296, jj = rest / 36, iv = rest % 36;
  int d = (kk * 36 + iv) * 36 + jj;
  #pragma unroll
  for (int rr = 0; rr < 16; rr++){
    NtT[(size_t)(rb + rr) * KCP + d] = acc[rr];
  }
}

extern "C" void kernel_launch(void* const* d_in, const int* in_sizes, int n_in,
                              void* d_out, int out_size, void* d_ws, size_t ws_size,
                              hipStream_t stream) {
  const float* inp = (const float*)d_in[0];
  const float* s0  = (const float*)d_in[1];
  const float* pa  = (const float*)d_in[2];
  const float* pb  = (const float*)d_in[3];
  const float* pg  = (const float*)d_in[4];
  float* ws  = (float*)d_ws;
  float* L   = ws + OFF_L;   float* S   = ws + OFF_S;    float* Mt  = ws + OFF_MT;
  float* NtT = ws + OFF_NTT; float* Big = ws + OFF_BIG;
  float* Up   = ws + OFF_UP;
  float* ACLp = ws + OFF_ACLP;
  float* Q    = ws + OFF_Q;
  float* Gr  = ws + OFF_GRAM;
  float* CmI = ws + OFF_CMI; float* CnI = ws + OFF_CNI;
  float* St  = ws + OFF_ST;
  float* out = (float*)d_out;

  k_init<<<2048, 256, 0, stream>>>(inp, s0, L, S, Mt, NtT);
  for (int step = 0; step < 5; step++){
    bool last = (step == 4);
    if (!last)
      k_gram<<<4096, 64, 0, stream>>>(NtT, KCP, KCP / 4, Gr);   // Cm raw = N@N^T
    // conv_R z==4 sentinel: inv(Cm) PHASE A -> state
    k_conv_R<<<dim3(64, 8, last ? 4 : 5), 64, 0, stream>>>(Mt, NtT, Big, Gr, pg, pa, St);
    k_reduce_LS<<<256, 256, 0, stream>>>(Big, inp, pg, pb, S, last ? out : L);
    if (last) break;
    // conv_T1 z==4 sentinel: inv(Cm) PHASE B -> CmI
    k_conv_T1<<<dim3(64, 8, 5), 64, 0, stream>>>(L, NtT, Big, St, CmI);
    k_mn<<<dim3(32, 2), 256, 0, stream>>>(Big, CmI, pg, Mt);
    k_gram<<<4096, 64, 0, stream>>>(Mt, 8192, 2048, Gr);        // Cn raw = Mn^T@Mn
    // ACL of L (c-partials) + sentinel block 256: full looped inv(Cn) -> CnI
    k_acl<<<257, 256, 0, stream>>>(L, ACLp, Gr, pg, pa, CnI);
    // U-partials from NtT_old x ACL; y==6 sentinel: Q = (2g)^2 CmI@CnI
    k_ucv<<<dim3(64, 7), 256, 0, stream>>>(NtT, ACLp, Up, CmI, CnI, pg, Q);
    // NtT_new = Q^T-weighted sum of U-partials (in-place over NtT)
    k_nn2<<<dim3(11, 4), 256, 0, stream>>>(Up, Q, NtT);
  }
}